// Round 1
// baseline (348.428 us; speedup 1.0000x reference)
//
#include <hip/hip_runtime.h>

#define NB    2          // batch
#define NDST  131072
#define NSRC  131072
#define FF    64
#define EE    524288
#define EPSV  1e-8f

// Phase 1: per-destination weight sums via atomics.
__global__ void norm_kernel(const int* __restrict__ dst,
                            const float* __restrict__ wts,
                            float* __restrict__ norm) {
    int e = blockIdx.x * blockDim.x + threadIdx.x;
    if (e < EE) {
        atomicAdd(&norm[dst[e]], wts[e]);
    }
}

// Phase 3: scatter-add. One thread per (edge, f); loop over batch b.
// Within a wave: 64 consecutive f for the same edge -> coalesced 256B x read
// and a contiguous 256B run of fp32 atomics into out.
__global__ void scatter_kernel(const float* __restrict__ x,
                               const int* __restrict__ src,
                               const int* __restrict__ dst,
                               const float* __restrict__ wts,
                               const float* __restrict__ norm,
                               float* __restrict__ out) {
    int tid = blockIdx.x * blockDim.x + threadIdx.x;   // tid = e*64 + f
    int e = tid >> 6;
    int f = tid & 63;
    if (e >= EE) return;

    int s = src[e];
    int d = dst[e];
    float w = wts[e] / (norm[d] + EPSV);

    #pragma unroll
    for (int b = 0; b < NB; ++b) {
        float xv = x[(size_t)b * NSRC * FF + (size_t)s * FF + f];
        atomicAdd(&out[(size_t)b * NDST * FF + (size_t)d * FF + f], w * xv);
    }
}

extern "C" void kernel_launch(void* const* d_in, const int* in_sizes, int n_in,
                              void* d_out, int out_size, void* d_ws, size_t ws_size,
                              hipStream_t stream) {
    const float* x          = (const float*)d_in[0];
    const int*   edge_index = (const int*)d_in[1];   // (2, E) int32 per harness
    const float* weights    = (const float*)d_in[2];

    const int* src = edge_index;        // edge_index[0]
    const int* dst = edge_index + EE;   // edge_index[1]

    float* out  = (float*)d_out;
    float* norm = (float*)d_ws;         // N_DST floats = 512 KiB scratch

    // d_ws and d_out are poisoned 0xAA before every timed launch — zero them.
    hipMemsetAsync(norm, 0, NDST * sizeof(float), stream);
    hipMemsetAsync(out, 0, (size_t)out_size * sizeof(float), stream);

    {
        int threads = 256;
        int blocks = (EE + threads - 1) / threads;
        norm_kernel<<<blocks, threads, 0, stream>>>(dst, weights, norm);
    }
    {
        long long total = (long long)EE * FF;
        int threads = 256;
        long long blocks = (total + threads - 1) / threads;
        scatter_kernel<<<(int)blocks, threads, 0, stream>>>(x, src, dst, weights, norm, out);
    }
}

// Round 2
// 247.967 us; speedup vs baseline: 1.4051x; 1.4051x over previous
//
#include <hip/hip_runtime.h>

#define NB    2
#define NDST  131072
#define NSRC  131072
#define FF    64
#define EE    524288
#define EPSV  1e-8f
#define SCAN_BLOCKS 512      // NDST / 256

// ---------- Phase A: histogram of dst ----------
__global__ void hist_kernel(const int* __restrict__ dst, int* __restrict__ counts) {
    int e = blockIdx.x * blockDim.x + threadIdx.x;
    if (e < EE) atomicAdd(&counts[dst[e]], 1);
}

// ---------- Phase B: exclusive scan of counts (3 kernels) ----------
__global__ void scan1_kernel(const int* __restrict__ counts,
                             int* __restrict__ offs, int* __restrict__ bsum) {
    __shared__ int tmp[256];
    int t = threadIdx.x;
    int i = blockIdx.x * 256 + t;
    int v = counts[i];
    tmp[t] = v; __syncthreads();
    for (int off = 1; off < 256; off <<= 1) {
        int add = (t >= off) ? tmp[t - off] : 0;
        __syncthreads();
        tmp[t] += add;
        __syncthreads();
    }
    offs[i] = tmp[t] - v;                     // exclusive within block
    if (t == 255) bsum[blockIdx.x] = tmp[t];  // block total
}

__global__ void scan2_kernel(int* __restrict__ bsum) {
    __shared__ int tmp[SCAN_BLOCKS];
    int t = threadIdx.x;
    int v = bsum[t];
    tmp[t] = v; __syncthreads();
    for (int off = 1; off < SCAN_BLOCKS; off <<= 1) {
        int add = (t >= off) ? tmp[t - off] : 0;
        __syncthreads();
        tmp[t] += add;
        __syncthreads();
    }
    bsum[t] = tmp[t] - v;                     // exclusive
}

__global__ void scan3_kernel(int* __restrict__ offs, const int* __restrict__ bsum,
                             int* __restrict__ cursor) {
    int i = blockIdx.x * 256 + threadIdx.x;
    int v = offs[i] + bsum[blockIdx.x];
    offs[i]   = v;
    cursor[i] = v;
    if (i == 0) offs[NDST] = EE;
}

// ---------- Phase C: counting-sort edges by dst ----------
__global__ void fill_kernel(const int* __restrict__ src, const int* __restrict__ dst,
                            const float* __restrict__ wts, int* __restrict__ cursor,
                            int* __restrict__ ssrc, float* __restrict__ sw) {
    int e = blockIdx.x * blockDim.x + threadIdx.x;
    if (e < EE) {
        int d = dst[e];
        int p = atomicAdd(&cursor[d], 1);
        ssrc[p] = src[e];
        sw[p]   = wts[e];
    }
}

// ---------- Phase D: one wave per dst row; register accumulate; single store ----------
// out[b,d,f] = (sum_e w_e * x[b, s_e, f]) / (sum_e w_e + eps)
__global__ __launch_bounds__(256) void gather_kernel(const float* __restrict__ x,
                                                     const int* __restrict__ offs,
                                                     const int* __restrict__ ssrc,
                                                     const float* __restrict__ sw,
                                                     float* __restrict__ out) {
    int gid  = blockIdx.x * blockDim.x + threadIdx.x;
    int d    = gid >> 6;       // one wave per destination node
    int lane = gid & 63;       // lane = feature index (F == 64)

    int begin = offs[d];
    int end   = offs[d + 1];

    float acc0 = 0.f, acc1 = 0.f, sumw = 0.f;
    for (int e = begin; e < end; ++e) {
        int   s  = ssrc[e];            // broadcast (all lanes same addr)
        float we = sw[e];
        sumw += we;
        float xv0 = x[(size_t)s * FF + lane];                          // b = 0
        float xv1 = x[(size_t)NSRC * FF + (size_t)s * FF + lane];      // b = 1
        acc0 += we * xv0;
        acc1 += we * xv1;
    }
    float inv = 1.0f / (sumw + EPSV);
    out[(size_t)d * FF + lane]                        = acc0 * inv;    // b = 0
    out[(size_t)NDST * FF + (size_t)d * FF + lane]    = acc1 * inv;    // b = 1
}

extern "C" void kernel_launch(void* const* d_in, const int* in_sizes, int n_in,
                              void* d_out, int out_size, void* d_ws, size_t ws_size,
                              hipStream_t stream) {
    const float* x          = (const float*)d_in[0];
    const int*   edge_index = (const int*)d_in[1];   // (2, E) int32
    const float* weights    = (const float*)d_in[2];

    const int* src = edge_index;
    const int* dst = edge_index + EE;
    float* out = (float*)d_out;

    // Workspace layout (ints/floats, 4 B each):
    int*   wsi    = (int*)d_ws;
    int*   counts = wsi;                               // NDST (reused as cursor)
    int*   offs   = wsi + NDST;                        // NDST + 1
    int*   bsum   = wsi + 2 * NDST + 8;                // SCAN_BLOCKS
    int*   ssrc   = wsi + 2 * NDST + 8 + SCAN_BLOCKS;  // EE
    float* sw     = (float*)(ssrc + EE);               // EE

    // counts must start at zero (ws is poisoned 0xAA each call)
    hipMemsetAsync(counts, 0, NDST * sizeof(int), stream);

    hist_kernel<<<EE / 256, 256, 0, stream>>>(dst, counts);
    scan1_kernel<<<SCAN_BLOCKS, 256, 0, stream>>>(counts, offs, bsum);
    scan2_kernel<<<1, SCAN_BLOCKS, 0, stream>>>(bsum);
    scan3_kernel<<<SCAN_BLOCKS, 256, 0, stream>>>(offs, bsum, counts /*cursor*/);
    fill_kernel<<<EE / 256, 256, 0, stream>>>(src, dst, weights, counts /*cursor*/, ssrc, sw);
    gather_kernel<<<(NDST * 64) / 256, 256, 0, stream>>>(x, offs, ssrc, sw, out);
}

// Round 3
// 219.353 us; speedup vs baseline: 1.5884x; 1.1305x over previous
//
#include <hip/hip_runtime.h>

#define NB    2
#define NDST  131072
#define NSRC  131072
#define FF    64
#define EE    524288
#define EPSV  1e-8f
#define SCAN_BLOCKS 512      // NDST / 256

typedef unsigned long long u64;

// ---------- Phase A: histogram of dst ----------
__global__ void hist_kernel(const int* __restrict__ dst, int* __restrict__ counts) {
    int e = blockIdx.x * blockDim.x + threadIdx.x;
    if (e < EE) atomicAdd(&counts[dst[e]], 1);
}

// ---------- Phase B: exclusive scan of counts (3 kernels) ----------
__global__ void scan1_kernel(const int* __restrict__ counts,
                             int* __restrict__ offs, int* __restrict__ bsum) {
    __shared__ int tmp[256];
    int t = threadIdx.x;
    int i = blockIdx.x * 256 + t;
    int v = counts[i];
    tmp[t] = v; __syncthreads();
    for (int off = 1; off < 256; off <<= 1) {
        int add = (t >= off) ? tmp[t - off] : 0;
        __syncthreads();
        tmp[t] += add;
        __syncthreads();
    }
    offs[i] = tmp[t] - v;                     // exclusive within block
    if (t == 255) bsum[blockIdx.x] = tmp[t];  // block total
}

__global__ void scan2_kernel(int* __restrict__ bsum) {
    __shared__ int tmp[SCAN_BLOCKS];
    int t = threadIdx.x;
    int v = bsum[t];
    tmp[t] = v; __syncthreads();
    for (int off = 1; off < SCAN_BLOCKS; off <<= 1) {
        int add = (t >= off) ? tmp[t - off] : 0;
        __syncthreads();
        tmp[t] += add;
        __syncthreads();
    }
    bsum[t] = tmp[t] - v;                     // exclusive
}

__global__ void scan3_kernel(int* __restrict__ offs, const int* __restrict__ bsum,
                             int* __restrict__ cursor) {
    int i = blockIdx.x * 256 + threadIdx.x;
    int v = offs[i] + bsum[blockIdx.x];
    offs[i]   = v;
    cursor[i] = v;
    if (i == 0) offs[NDST] = EE;
}

// ---------- Phase C: counting-sort edges by dst, packed (w<<32 | src) ----------
__global__ void fill_kernel(const int* __restrict__ src, const int* __restrict__ dst,
                            const float* __restrict__ wts, int* __restrict__ cursor,
                            u64* __restrict__ rec) {
    int e = blockIdx.x * blockDim.x + threadIdx.x;
    if (e < EE) {
        int d = dst[e];
        int p = atomicAdd(&cursor[d], 1);
        u64 r = ((u64)__float_as_uint(wts[e]) << 32) | (unsigned)src[e];
        rec[p] = r;
    }
}

// ---------- Phase D: one wave per dst; unroll-4 segment loop; nt out stores ----------
// out[b,d,f] = (sum_e w_e * x[b, s_e, f]) / (sum_e w_e + eps)
__global__ __launch_bounds__(256) void gather_kernel(const float* __restrict__ x,
                                                     const int* __restrict__ offs,
                                                     const u64* __restrict__ rec,
                                                     float* __restrict__ out) {
    int gid  = blockIdx.x * blockDim.x + threadIdx.x;
    int d    = gid >> 6;       // one wave per destination node
    int lane = gid & 63;       // lane = feature index (F == 64)

    int begin = offs[d];
    int end   = offs[d + 1];

    const float* xb0 = x + lane;                          // b = 0
    const float* xb1 = x + (size_t)NSRC * FF + lane;      // b = 1

    float acc0 = 0.f, acc1 = 0.f, sumw = 0.f;
    int e = begin;
    for (; e + 4 <= end; e += 4) {
        u64 r0 = rec[e + 0];
        u64 r1 = rec[e + 1];
        u64 r2 = rec[e + 2];
        u64 r3 = rec[e + 3];
        int s0 = (int)(unsigned)r0;  float w0 = __uint_as_float((unsigned)(r0 >> 32));
        int s1 = (int)(unsigned)r1;  float w1 = __uint_as_float((unsigned)(r1 >> 32));
        int s2 = (int)(unsigned)r2;  float w2 = __uint_as_float((unsigned)(r2 >> 32));
        int s3 = (int)(unsigned)r3;  float w3 = __uint_as_float((unsigned)(r3 >> 32));
        float a00 = xb0[(size_t)s0 * FF];
        float a10 = xb0[(size_t)s1 * FF];
        float a20 = xb0[(size_t)s2 * FF];
        float a30 = xb0[(size_t)s3 * FF];
        float a01 = xb1[(size_t)s0 * FF];
        float a11 = xb1[(size_t)s1 * FF];
        float a21 = xb1[(size_t)s2 * FF];
        float a31 = xb1[(size_t)s3 * FF];
        sumw += (w0 + w1) + (w2 + w3);
        acc0 = fmaf(w0, a00, fmaf(w1, a10, fmaf(w2, a20, fmaf(w3, a30, acc0))));
        acc1 = fmaf(w0, a01, fmaf(w1, a11, fmaf(w2, a21, fmaf(w3, a31, acc1))));
    }
    for (; e < end; ++e) {
        u64 r = rec[e];
        int s = (int)(unsigned)r;
        float w = __uint_as_float((unsigned)(r >> 32));
        sumw += w;
        acc0 = fmaf(w, xb0[(size_t)s * FF], acc0);
        acc1 = fmaf(w, xb1[(size_t)s * FF], acc1);
    }
    float inv = 1.0f / (sumw + EPSV);
    __builtin_nontemporal_store(acc0 * inv, &out[(size_t)d * FF + lane]);
    __builtin_nontemporal_store(acc1 * inv, &out[(size_t)NDST * FF + (size_t)d * FF + lane]);
}

extern "C" void kernel_launch(void* const* d_in, const int* in_sizes, int n_in,
                              void* d_out, int out_size, void* d_ws, size_t ws_size,
                              hipStream_t stream) {
    const float* x          = (const float*)d_in[0];
    const int*   edge_index = (const int*)d_in[1];   // (2, E) int32
    const float* weights    = (const float*)d_in[2];

    const int* src = edge_index;
    const int* dst = edge_index + EE;
    float* out = (float*)d_out;

    // Workspace layout (4 B units):
    int* wsi    = (int*)d_ws;
    int* counts = wsi;                               // NDST (reused as cursor)
    int* offs   = wsi + NDST;                        // NDST + 1
    int* bsum   = wsi + 2 * NDST + 8;                // SCAN_BLOCKS
    u64* rec    = (u64*)(wsi + 2 * NDST + 8 + SCAN_BLOCKS);  // EE u64 (8B-aligned)

    // counts must start at zero (ws is poisoned 0xAA each call)
    hipMemsetAsync(counts, 0, NDST * sizeof(int), stream);

    hist_kernel<<<EE / 256, 256, 0, stream>>>(dst, counts);
    scan1_kernel<<<SCAN_BLOCKS, 256, 0, stream>>>(counts, offs, bsum);
    scan2_kernel<<<1, SCAN_BLOCKS, 0, stream>>>(bsum);
    scan3_kernel<<<SCAN_BLOCKS, 256, 0, stream>>>(offs, bsum, counts /*cursor*/);
    fill_kernel<<<EE / 256, 256, 0, stream>>>(src, dst, weights, counts /*cursor*/, rec);
    gather_kernel<<<(NDST * 64) / 256, 256, 0, stream>>>(x, offs, rec, out);
}